// Round 5
// baseline (491.681 us; speedup 1.0000x reference)
//
#include <hip/hip_runtime.h>

// ---------------------------------------------------------------------------
// localAE: two GCNConv layers (128->64 encode, 64->128 decode), N=100000,
// E=1.6M.  out[n] = dinv[n] * (hs[n] + sum_{e: dst==n} hs[src_e]) + b
// where hs = (X @ W) * dinv[row],  dinv = rsqrt(1 + indegree).
//
// Round 5 == round 3 design, third submit (2x container infra failure, kernel
// never ran). Only change: __builtin_bit_cast -> __float_as_uint/
// __uint_as_float (most-standard HIP intrinsics) to rule out a source-
// triggered toolchain issue.
//  - compact exact CSR (count -> wave-scan offsets -> scatter)
//  - hs stored as bf16 (halves random gather traffic)
//  - agg kernels pipeline gathers 8-deep
// ---------------------------------------------------------------------------

using u32 = unsigned int;

__device__ inline unsigned short f2bf_rtne(float f) {
    u32 b = __float_as_uint(f);
    u32 r = (b + 0x7FFFu + ((b >> 16) & 1u)) >> 16;
    return (unsigned short)r;
}
__device__ inline float bf2f(unsigned short h) {
    return __uint_as_float(((u32)h) << 16);
}

__global__ __launch_bounds__(256)
void count_kernel(const int* __restrict__ dst, int E, int* __restrict__ cnt) {
    int i = blockIdx.x * 256 + threadIdx.x;
    if (i < E) atomicAdd(&cnt[dst[i]], 1);
}

// dinv = rsqrt(cnt+1); off[] = exclusive prefix allocation of cnt[] via a
// wave-level shfl scan + ONE global atomic per wave (order across waves is
// irrelevant: each node just needs an exclusive contiguous range).
__global__ __launch_bounds__(256)
void dinv_off_kernel(const int* __restrict__ cnt, float* __restrict__ dinv,
                     int* __restrict__ off, int* __restrict__ gcur, int M)
{
    const int i    = blockIdx.x * 256 + threadIdx.x;
    const int lane = threadIdx.x & 63;
    const int c    = (i < M) ? cnt[i] : 0;
    if (i < M) dinv[i] = rsqrtf((float)c + 1.0f);

    int s = c;                                  // inclusive wave scan
    #pragma unroll
    for (int d = 1; d < 64; d <<= 1) {
        int t = __shfl_up(s, d, 64);
        if (lane >= d) s += t;
    }
    int base = 0;
    if (lane == 63) base = atomicAdd(gcur, s);  // s == wave total at lane 63
    base = __shfl(base, 63, 64);
    if (i < M) off[i] = base + s - c;
}

__global__ __launch_bounds__(256)
void scatter_kernel(const int* __restrict__ src, const int* __restrict__ dst,
                    int E, const int* __restrict__ off, int* __restrict__ cursor,
                    int* __restrict__ csr)
{
    int i = blockIdx.x * 256 + threadIdx.x;
    if (i < E) {
        const int d = dst[i];
        const int p = atomicAdd(&cursor[d], 1);
        const int idx = off[d] + p;
        if (idx < E) csr[idx] = src[i];       // defensive; sum(cnt) == E exactly
    }
}

// GEMM  hs[m, :] = bf16( (X[m, :] @ W) * dinv[m] ).
template<int K, int N>
__global__ __launch_bounds__(256)
void gemm_scale_bf16(const float* __restrict__ X, const float* __restrict__ W,
                     const float* __restrict__ dinv,
                     unsigned short* __restrict__ hs, int M)
{
    constexpr int TM  = 64;
    constexpr int QPR = K / 4;
    __shared__ float Ws[K * N];
    __shared__ float Xs[TM * K];

    const int tid  = threadIdx.x;
    const int row0 = blockIdx.x * TM;

    for (int i = tid; i < K * N / 4; i += 256) {
        float4 v = reinterpret_cast<const float4*>(W)[i];
        *reinterpret_cast<float4*>(&Ws[i * 4]) = v;
    }
    for (int i = tid; i < TM * QPR; i += 256) {
        int r = i / QPR, q = i - r * QPR;
        int gr = row0 + r;
        float4 v = make_float4(0.f, 0.f, 0.f, 0.f);
        if (gr < M) v = reinterpret_cast<const float4*>(X)[(size_t)gr * QPR + q];
        *reinterpret_cast<float4*>(&Xs[r * K + q * 4]) = v;
    }
    __syncthreads();

    constexpr int CG  = N / 4;
    constexpr int RPT = N / 16;
    const int c0 = (tid % CG) * 4;
    const int r0 = (tid / CG) * RPT;

    float a[RPT][4];
    #pragma unroll
    for (int rr = 0; rr < RPT; ++rr) {
        a[rr][0] = 0.f; a[rr][1] = 0.f; a[rr][2] = 0.f; a[rr][3] = 0.f;
    }

    #pragma unroll 4
    for (int k = 0; k < K; ++k) {
        const float4 wv = *reinterpret_cast<const float4*>(&Ws[k * N + c0]);
        #pragma unroll
        for (int rr = 0; rr < RPT; ++rr) {
            const float xv = Xs[(r0 + rr) * K + k];
            a[rr][0] += xv * wv.x;
            a[rr][1] += xv * wv.y;
            a[rr][2] += xv * wv.z;
            a[rr][3] += xv * wv.w;
        }
    }

    #pragma unroll
    for (int rr = 0; rr < RPT; ++rr) {
        const int gr = row0 + r0 + rr;
        if (gr < M) {
            const float d = dinv[gr];
            ushort4 o;
            o.x = f2bf_rtne(a[rr][0] * d);
            o.y = f2bf_rtne(a[rr][1] * d);
            o.z = f2bf_rtne(a[rr][2] * d);
            o.w = f2bf_rtne(a[rr][3] * d);
            *reinterpret_cast<ushort4*>(&hs[(size_t)gr * N + c0]) = o;
        }
    }
}

// Wave-per-node gather aggregation (C=64), 8-deep pipelined, finalize fused.
__global__ __launch_bounds__(256)
void gcn_agg64(const unsigned short* __restrict__ hs, const int* __restrict__ csr,
               const int* __restrict__ off, const int* __restrict__ cnt,
               const float* __restrict__ dinv, const float* __restrict__ bias,
               float* __restrict__ out, int M)
{
    const int lane = threadIdx.x & 63;
    int n = (blockIdx.x * 256 + threadIdx.x) >> 6;
    if (n >= M) return;
    n = __builtin_amdgcn_readfirstlane(n);
    const int deg = cnt[n];
    const int* __restrict__ lst = csr + off[n];
    const float dv = dinv[n];

    float acc = bf2f(hs[(size_t)n * 64 + lane]);
    int j = 0;
    for (; j + 8 <= deg; j += 8) {
        const int s0 = lst[j + 0], s1 = lst[j + 1], s2 = lst[j + 2], s3 = lst[j + 3];
        const int s4 = lst[j + 4], s5 = lst[j + 5], s6 = lst[j + 6], s7 = lst[j + 7];
        const float v0 = bf2f(hs[(size_t)s0 * 64 + lane]);
        const float v1 = bf2f(hs[(size_t)s1 * 64 + lane]);
        const float v2 = bf2f(hs[(size_t)s2 * 64 + lane]);
        const float v3 = bf2f(hs[(size_t)s3 * 64 + lane]);
        const float v4 = bf2f(hs[(size_t)s4 * 64 + lane]);
        const float v5 = bf2f(hs[(size_t)s5 * 64 + lane]);
        const float v6 = bf2f(hs[(size_t)s6 * 64 + lane]);
        const float v7 = bf2f(hs[(size_t)s7 * 64 + lane]);
        acc += (((v0 + v1) + (v2 + v3)) + ((v4 + v5) + (v6 + v7)));
    }
    for (; j < deg; ++j) acc += bf2f(hs[(size_t)lst[j] * 64 + lane]);
    out[(size_t)n * 64 + lane] = acc * dv + bias[lane];
}

// C=128: lane holds channels (2c, 2c+1) as one bf16x2 (ushort2) load.
__global__ __launch_bounds__(256)
void gcn_agg128(const unsigned short* __restrict__ hs, const int* __restrict__ csr,
                const int* __restrict__ off, const int* __restrict__ cnt,
                const float* __restrict__ dinv, const float* __restrict__ bias,
                float* __restrict__ out, int M)
{
    const int lane = threadIdx.x & 63;
    int n = (blockIdx.x * 256 + threadIdx.x) >> 6;
    if (n >= M) return;
    n = __builtin_amdgcn_readfirstlane(n);
    const int deg = cnt[n];
    const int* __restrict__ lst = csr + off[n];
    const float dv = dinv[n];
    const ushort2* __restrict__ h2 = reinterpret_cast<const ushort2*>(hs);

    ushort2 self = h2[(size_t)n * 64 + lane];
    float ax = bf2f(self.x), ay = bf2f(self.y);
    int j = 0;
    for (; j + 8 <= deg; j += 8) {
        const int s0 = lst[j + 0], s1 = lst[j + 1], s2 = lst[j + 2], s3 = lst[j + 3];
        const int s4 = lst[j + 4], s5 = lst[j + 5], s6 = lst[j + 6], s7 = lst[j + 7];
        const ushort2 v0 = h2[(size_t)s0 * 64 + lane];
        const ushort2 v1 = h2[(size_t)s1 * 64 + lane];
        const ushort2 v2 = h2[(size_t)s2 * 64 + lane];
        const ushort2 v3 = h2[(size_t)s3 * 64 + lane];
        const ushort2 v4 = h2[(size_t)s4 * 64 + lane];
        const ushort2 v5 = h2[(size_t)s5 * 64 + lane];
        const ushort2 v6 = h2[(size_t)s6 * 64 + lane];
        const ushort2 v7 = h2[(size_t)s7 * 64 + lane];
        ax += (((bf2f(v0.x) + bf2f(v1.x)) + (bf2f(v2.x) + bf2f(v3.x))) +
               ((bf2f(v4.x) + bf2f(v5.x)) + (bf2f(v6.x) + bf2f(v7.x))));
        ay += (((bf2f(v0.y) + bf2f(v1.y)) + (bf2f(v2.y) + bf2f(v3.y))) +
               ((bf2f(v4.y) + bf2f(v5.y)) + (bf2f(v6.y) + bf2f(v7.y))));
    }
    for (; j < deg; ++j) {
        const ushort2 v = h2[(size_t)lst[j] * 64 + lane];
        ax += bf2f(v.x); ay += bf2f(v.y);
    }
    const float2 b2 = reinterpret_cast<const float2*>(bias)[lane];
    float2 o;
    o.x = ax * dv + b2.x;
    o.y = ay * dv + b2.y;
    reinterpret_cast<float2*>(out)[(size_t)n * 64 + lane] = o;
}

extern "C" void kernel_launch(void* const* d_in, const int* in_sizes, int n_in,
                              void* d_out, int out_size, void* d_ws, size_t ws_size,
                              hipStream_t stream)
{
    const float* x    = (const float*)d_in[0];   // [M,128]
    const int*   ei   = (const int*)  d_in[1];   // [2,E]
    const float* Wenc = (const float*)d_in[2];   // [128,64]
    const float* benc = (const float*)d_in[3];   // [64]
    const float* Wdec = (const float*)d_in[4];   // [64,128]
    const float* bdec = (const float*)d_in[5];   // [128]

    const int M = in_sizes[0] / 128;             // 100000
    const int E = in_sizes[1] / 2;               // 1600000
    const int* src  = ei;
    const int* dstv = ei + E;

    float* emb   = (float*)d_out;                       // [M,64] f32
    float* recon = (float*)d_out + (size_t)M * 64;      // [M,128] f32

    // workspace layout (bytes):
    //   hs     : M*128 bf16  (25.6 MB)   [also used as M*64 for layer 1]
    //   dinv   : M f32
    //   off    : M int
    //   cnt    : M int   |
    //   cursor : M int   |  zeroed with ONE memset
    //   gcur   : 1 int   |
    //   csr    : E int   (6.4 MB)
    unsigned short* hs = (unsigned short*)d_ws;
    char* p = (char*)d_ws + (size_t)M * 128 * 2;
    float* dinv   = (float*)p;                 p += (size_t)M * 4;
    int*   off    = (int*)p;                   p += (size_t)M * 4;
    int*   cnt    = (int*)p;                   p += (size_t)M * 4;
    int*   cursor = (int*)p;                   p += (size_t)M * 4;
    int*   gcur   = (int*)p;                   p += 4;
    int*   csr    = (int*)p;

    // zero cnt+cursor+gcur in one shot (contiguous)
    hipMemsetAsync(cnt, 0, ((size_t)M * 2 + 1) * sizeof(int), stream);

    count_kernel<<<(E + 255) / 256, 256, 0, stream>>>(dstv, E, cnt);
    dinv_off_kernel<<<(M + 255) / 256, 256, 0, stream>>>(cnt, dinv, off, gcur, M);
    scatter_kernel<<<(E + 255) / 256, 256, 0, stream>>>(src, dstv, E, off, cursor, csr);

    const int aggBlocks = (M + 3) / 4;   // 4 waves (nodes) per 256-thread block

    // ---- layer 1: encode 128 -> 64 ----
    gemm_scale_bf16<128, 64><<<(M + 63) / 64, 256, 0, stream>>>(x, Wenc, dinv, hs, M);
    gcn_agg64<<<aggBlocks, 256, 0, stream>>>(hs, csr, off, cnt, dinv, benc, emb, M);

    // ---- layer 2: decode 64 -> 128 ----
    gemm_scale_bf16<64, 128><<<(M + 63) / 64, 256, 0, stream>>>(emb, Wdec, dinv, hs, M);
    gcn_agg128<<<aggBlocks, 256, 0, stream>>>(hs, csr, off, cnt, dinv, bdec, recon, M);
}